// Round 1
// baseline (1060.313 us; speedup 1.0000x reference)
//
#include <hip/hip_runtime.h>
#include <hip/hip_bf16.h>

// RingConv2d: out[b,o,i,j] = sum_{c,kh,kw} cos(xpad[b,c,i+kh,j+kw] - w[o,c,kh,kw])
// cos(a-b) = cos a cos b + sin a sin b -> two fused 3x3 convs over (cos,sin) pairs.
// Padded zero angle contributes (cos,sin) = (1,0).

#define B_ 32
#define C_ 64
#define H_ 64
#define W_ 64
#define O_ 128
#define CC 8   // channel chunk staged in LDS

// ---------------- prep: trig of x -> float2 (cos,sin), same [b][c][h][w] layout
__global__ __launch_bounds__(256) void prep_x(const float* __restrict__ x,
                                              float2* __restrict__ xt, int n) {
    int t = blockIdx.x * 256 + threadIdx.x;
    if (t >= n) return;
    float v = x[t];
    float s, c;
    __sincosf(v, &s, &c);
    xt[t] = make_float2(c, s);
}

// ---------------- prep: trig of w, transpose OIHW -> [c*9+k][o] float2
__global__ __launch_bounds__(256) void prep_w(const float* __restrict__ w,
                                              float2* __restrict__ wt) {
    int t = blockIdx.x * 256 + threadIdx.x;   // t over 128*64*9
    if (t >= O_ * C_ * 9) return;
    int o = t / (C_ * 9);
    int rem = t % (C_ * 9);                   // c*9 + k
    float v = w[t];                           // w[o][c][kh][kw] flat
    float s, c;
    sincosf(v, &s, &c);
    wt[rem * O_ + o] = make_float2(c, s);
}

// ---------------- conv: block tile 32 o x 16x16 spatial, one b
// threads: 256 = 4 o-groups (8 o each) x 64 spatial threads (8x8 of 2x2 px)
__global__ __launch_bounds__(256, 4) void ring_conv(const float2* __restrict__ X,
                                                    const float2* __restrict__ Wt,
                                                    float* __restrict__ out) {
    __shared__ float2 xs[CC][18][18];       // 20736 B
    __shared__ float2 wsh[CC][9][32];       // 18432 B

    const int blk = blockIdx.x;             // 2048 blocks
    const int jt = blk & 3;
    const int it = (blk >> 2) & 3;
    const int ot = (blk >> 4) & 3;
    const int b  = blk >> 6;

    const int tx = threadIdx.x;
    const int og = tx >> 6;                 // 0..3 (uniform per wave)
    const int sp = tx & 63;
    const int ti = sp >> 3;                 // 0..7
    const int tj = sp & 7;                  // 0..7

    const int i0 = it * 16 + ti * 2;        // global output row base
    const int j0 = jt * 16 + tj * 2;        // global output col base
    const int obase = ot * 32 + og * 8;

    float acc[8][4];
#pragma unroll
    for (int a = 0; a < 8; ++a)
#pragma unroll
        for (int p = 0; p < 4; ++p) acc[a][p] = 0.f;

    const int rbase = it * 16 - 1;          // x tile row base (global, with halo)
    const int cbase = jt * 16 - 1;

    for (int c0 = 0; c0 < C_; c0 += CC) {
        __syncthreads();
        // stage x tile: CC x 18 x 18 float2
        for (int idx = tx; idx < CC * 18 * 18; idx += 256) {
            int cc  = idx / 324;
            int r   = (idx % 324) / 18;
            int col = idx % 18;
            int gi = rbase + r;
            int gj = cbase + col;
            float2 v = make_float2(1.f, 0.f);   // padded angle 0 -> (cos,sin)=(1,0)
            if ((unsigned)gi < (unsigned)H_ && (unsigned)gj < (unsigned)W_)
                v = X[(((size_t)b * C_ + (c0 + cc)) * H_ + gi) * W_ + gj];
            xs[cc][r][col] = v;
        }
        // stage w tile: CC x 9 x 32 float2 (contiguous in Wt)
        for (int idx = tx; idx < CC * 9 * 32; idx += 256) {
            int cc = idx / 288;
            int k  = (idx % 288) / 32;
            int o  = idx % 32;
            wsh[cc][k][o] = Wt[((c0 + cc) * 9 + k) * O_ + ot * 32 + o];
        }
        __syncthreads();

        for (int cc = 0; cc < CC; ++cc) {
#pragma unroll
            for (int kh = 0; kh < 3; ++kh) {
#pragma unroll
                for (int kw = 0; kw < 3; ++kw) {
                    float2 xv0 = xs[cc][ti * 2 + kh][tj * 2 + kw];
                    float2 xv1 = xs[cc][ti * 2 + kh][tj * 2 + kw + 1];
                    float2 xv2 = xs[cc][ti * 2 + kh + 1][tj * 2 + kw];
                    float2 xv3 = xs[cc][ti * 2 + kh + 1][tj * 2 + kw + 1];
                    // 8 o's weights: 8 float2 contiguous -> read as 4 float4
                    const float4* wq = (const float4*)&wsh[cc][kh * 3 + kw][og * 8];
#pragma unroll
                    for (int q = 0; q < 4; ++q) {
                        float4 wv = wq[q];      // {cos(o0),sin(o0),cos(o1),sin(o1)}
                        int a0 = q * 2, a1 = q * 2 + 1;
                        acc[a0][0] += xv0.x * wv.x + xv0.y * wv.y;
                        acc[a0][1] += xv1.x * wv.x + xv1.y * wv.y;
                        acc[a0][2] += xv2.x * wv.x + xv2.y * wv.y;
                        acc[a0][3] += xv3.x * wv.x + xv3.y * wv.y;
                        acc[a1][0] += xv0.x * wv.z + xv0.y * wv.w;
                        acc[a1][1] += xv1.x * wv.z + xv1.y * wv.w;
                        acc[a1][2] += xv2.x * wv.z + xv2.y * wv.w;
                        acc[a1][3] += xv3.x * wv.z + xv3.y * wv.w;
                    }
                }
            }
        }
    }

    // epilogue: 8 o x 2x2 px per thread
#pragma unroll
    for (int a = 0; a < 8; ++a) {
        int o = obase + a;
        float* p = out + (((size_t)b * O_ + o) * H_ + i0) * W_ + j0;
        p[0]      = acc[a][0];
        p[1]      = acc[a][1];
        p[W_]     = acc[a][2];
        p[W_ + 1] = acc[a][3];
    }
}

extern "C" void kernel_launch(void* const* d_in, const int* in_sizes, int n_in,
                              void* d_out, int out_size, void* d_ws, size_t ws_size,
                              hipStream_t stream) {
    const float* x = (const float*)d_in[0];   // 32*64*64*64
    const float* w = (const float*)d_in[1];   // 128*64*3*3
    float* out = (float*)d_out;               // 32*128*64*64

    const int nx = B_ * C_ * H_ * W_;         // 8388608
    const int nw = O_ * C_ * 9;               // 73728

    float2* xt = (float2*)d_ws;                       // 67.1 MB
    float2* wt = (float2*)((char*)d_ws + (size_t)nx * sizeof(float2));  // +0.59 MB

    prep_x<<<(nx + 255) / 256, 256, 0, stream>>>(x, xt, nx);
    prep_w<<<(nw + 255) / 256, 256, 0, stream>>>(w, wt);

    // grid: b(32) x ot(4) x it(4) x jt(4) = 2048 blocks
    ring_conv<<<2048, 256, 0, stream>>>(xt, wt, out);
}

// Round 3
// 80.166 us; speedup vs baseline: 13.2265x; 13.2265x over previous
//
#include <hip/hip_runtime.h>
#include <hip/hip_bf16.h>

// RingConv2d via f16 MFMA implicit GEMM.
// out[b,o,i,j] = sum_{c,kh,kw} cos(xpad - w) = cosconv + sinconv
// GEMM: M=o(128), N=px(32*64*64), K=1152 = 4 cgroups x 9 taps x (16c x 2trig)
// MFMA 16x16x32_f16: per-lane k = {4g+j (j<4), 16+4g+(j-4)}, g=lane>>4
//   A: row(M)=lane&15, B: col(N)=lane&15, D: col=lane&15, row=4g+reg

typedef _Float16 half8 __attribute__((ext_vector_type(8)));
typedef float f32x4 __attribute__((ext_vector_type(4)));

#define NB 32
#define NC 64
#define NH 64
#define NW 64
#define NO 128

union U16 { unsigned short u; _Float16 h; };
union HB { uint4 u4; unsigned long long q[2]; half8 h; };

__device__ inline unsigned pack_cs(float ang) {
    float s, c;
    sincosf(ang, &s, &c);
    U16 uc, us; uc.h = (_Float16)c; us.h = (_Float16)s;
    return (unsigned)uc.u | ((unsigned)us.u << 16);   // cos low, sin high (k=c*2+t)
}

__device__ inline unsigned pack_cs_fast(float ang) {
    float s, c;
    __sincosf(ang, &s, &c);
    U16 uc, us; uc.h = (_Float16)c; us.h = (_Float16)s;
    return (unsigned)uc.u | ((unsigned)us.u << 16);
}

// ---- prep x: [b][c][h][w] f32 -> xp[b][cg4][row][col] 64B = 16 c_sub x (cos,sin) f16
__global__ __launch_bounds__(256) void prep_x(const float* __restrict__ x,
                                              unsigned* __restrict__ xp) {
    __shared__ unsigned ls[64 * 65];
    const int b = blockIdx.x >> 6, row = blockIdx.x & 63;
    const int t = threadIdx.x;
#pragma unroll
    for (int pass = 0; pass < 16; ++pass) {
        int c = pass * 4 + (t >> 6);
        int col = t & 63;
        float v = x[((size_t)(b * NC + c) * NH + row) * NW + col];
        ls[c * 65 + col] = pack_cs_fast(v);
    }
    __syncthreads();
    const int q = t & 3, col = t >> 2;          // col 0..63, q = c_sub quad
#pragma unroll
    for (int cg = 0; cg < 4; ++cg) {
        uint4 vv;
        vv.x = ls[(cg * 16 + 4 * q + 0) * 65 + col];
        vv.y = ls[(cg * 16 + 4 * q + 1) * 65 + col];
        vv.z = ls[(cg * 16 + 4 * q + 2) * 65 + col];
        vv.w = ls[(cg * 16 + 4 * q + 3) * 65 + col];
        ((uint4*)xp)[(size_t)(((b * 4 + cg) * 64 + row) * 64 + col) * 4 + q] = vv;
    }
}

// ---- prep w: OIHW f32 -> wq[chunk36][o128][g4] 16B = A-fragment order
__global__ __launch_bounds__(256) void prep_w(const float* __restrict__ w,
                                              uint4* __restrict__ wq) {
    int t = blockIdx.x * 256 + threadIdx.x;     // 36*128*4 = 18432
    if (t >= 36 * 128 * 4) return;
    int g = t & 3, o = (t >> 2) & 127, chunk = t >> 9;
    int cg = chunk / 9, kpos = chunk % 9, kh = kpos / 3, kw = kpos % 3;
    unsigned r[4];
#pragma unroll
    for (int m = 0; m < 4; ++m) {
        int c_sub = (m < 2) ? (2 * g + m) : (8 + 2 * g + (m - 2));
        int c = cg * 16 + c_sub;
        float ang = w[((o * NC + c) * 3 + kh) * 3 + kw];
        r[m] = pack_cs(ang);
    }
    wq[t] = make_uint4(r[0], r[1], r[2], r[3]);
}

// ---- conv: block = 16x16 px x 64 o, 4 waves (wave w: rows 4w..4w+3, all 4 o-frags)
__global__ __launch_bounds__(256, 2) void ring_conv(const uint4* __restrict__ xp,
                                                    const uint4* __restrict__ wq,
                                                    float* __restrict__ out) {
    __shared__ __align__(16) char xs[18 * 18 * 72];   // 23328 B, 72B/pixel (64 payload + 8 pad)

    const int ob = blockIdx.x & 1;            // o-block: 0/1 -> o base 0/64
    const int pxb = blockIdx.x >> 1;          // 512 pixel blocks
    const int jt = pxb & 3, itile = (pxb >> 2) & 3, b = pxb >> 4;
    const int row0 = itile * 16, col0 = jt * 16;

    const int t = threadIdx.x, lane = t & 63, wid = t >> 6;
    const int l15 = lane & 15, g = lane >> 4;

    f32x4 acc[4][4] = {};                      // [px-row r][o-frag f]

    const int p_t = t >> 2, q = t & 3;         // staging: 4 threads per pixel

    for (int cg = 0; cg < 4; ++cg) {
        __syncthreads();
        const uint4* src = xp + (size_t)(b * 4 + cg) * 64 * 64 * 4;
#pragma unroll
        for (int pass = 0; pass < 6; ++pass) {
            int p = pass * 64 + p_t;
            if (p < 324) {
                int rr = p / 18, cc = p % 18;
                int gr = row0 - 1 + rr, gc = col0 - 1 + cc;
                uint4 v;
                if ((unsigned)gr < 64u && (unsigned)gc < 64u)
                    v = src[(size_t)(gr * 64 + gc) * 4 + q];
                else
                    v = make_uint4(0x3C00u, 0x3C00u, 0x3C00u, 0x3C00u); // (cos,sin)=(1,0)
                char* dst = xs + (rr * 18 + cc) * 72 + q * 16;
                unsigned long long lo = (unsigned long long)v.x | ((unsigned long long)v.y << 32);
                unsigned long long hi = (unsigned long long)v.z | ((unsigned long long)v.w << 32);
                *(unsigned long long*)dst = lo;
                *(unsigned long long*)(dst + 8) = hi;
            }
        }
        __syncthreads();

#pragma unroll
        for (int kpos = 0; kpos < 9; ++kpos) {
            const int kh = kpos / 3, kw = kpos % 3;
            const int chunk = cg * 9 + kpos;
            HB A[4];
#pragma unroll
            for (int f = 0; f < 4; ++f)
                A[f].u4 = wq[(size_t)(chunk * 128 + ob * 64 + f * 16 + l15) * 4 + g];
#pragma unroll
            for (int r = 0; r < 4; ++r) {
                int pix = (wid * 4 + r + kh) * 18 + l15 + kw;
                const char* sp = xs + pix * 72 + g * 8;
                HB Bv;
                Bv.q[0] = *(const unsigned long long*)sp;         // k = 4g+0..3
                Bv.q[1] = *(const unsigned long long*)(sp + 32);  // k = 16+4g+0..3
#pragma unroll
                for (int f = 0; f < 4; ++f)
                    acc[r][f] = __builtin_amdgcn_mfma_f32_16x16x32_f16(A[f].h, Bv.h,
                                                                       acc[r][f], 0, 0, 0);
            }
        }
    }

    // epilogue: D col = l15 = px col, row = 4g+i = o within frag
#pragma unroll
    for (int r = 0; r < 4; ++r) {
        int orow = row0 + wid * 4 + r;
#pragma unroll
        for (int f = 0; f < 4; ++f) {
            int o0 = ob * 64 + f * 16 + 4 * g;
            float* p = out + (((size_t)b * NO + o0) * NH + orow) * NW + col0 + l15;
#pragma unroll
            for (int i = 0; i < 4; ++i)
                p[(size_t)i * NH * NW] = acc[r][f][i];
        }
    }
}

extern "C" void kernel_launch(void* const* d_in, const int* in_sizes, int n_in,
                              void* d_out, int out_size, void* d_ws, size_t ws_size,
                              hipStream_t stream) {
    const float* x = (const float*)d_in[0];
    const float* w = (const float*)d_in[1];

    unsigned* xpnt = (unsigned*)d_ws;                                   // 32 MiB
    uint4* wqp = (uint4*)((char*)d_ws + (size_t)32 * 1024 * 1024);      // 288 KiB

    prep_x<<<NB * NH, 256, 0, stream>>>(x, xpnt);
    prep_w<<<72, 256, 0, stream>>>(w, wqp);
    ring_conv<<<1024, 256, 0, stream>>>((const uint4*)xpnt, wqp, (float*)d_out);
}